// Round 6
// baseline (126.407 us; speedup 1.0000x reference)
//
#include <hip/hip_runtime.h>
#include <hip/hip_bf16.h>

// Problem constants
#define BB 96    // batch
#define HH 100   // history length
#define NN 128   // candidates (broadcast only)
#define DD 768   // embed dim
#define AA 256   // attention dim

static __device__ __forceinline__ float dot4(float4 a, float4 b) {
  return a.x * b.x + a.y * b.y + a.z * b.z + a.w * b.w;
}

// ---------------------------------------------------------------------------
// D1 k_prep: grid-decoded fusion of all input-independent work:
//   blocks [0,576)    : transpose Wr (768x768) -> WrT
//   blocks [576,768)  : transpose WK (256x768) -> WKT
//   blocks [768,1536) : neigh partial sums -> neighp[8][B][D]
// ---------------------------------------------------------------------------
__global__ void k_prep(const float* __restrict__ Wr, const float* __restrict__ WK,
                       const float* __restrict__ hist,
                       float* __restrict__ WrT, float* __restrict__ WKT,
                       float* __restrict__ neighp) {
  __shared__ float tile[32][33];
  int bid = blockIdx.x;
  if (bid < 768) {
    const float* src; float* dst; int R, C, bx, by;
    if (bid < 576) { src = Wr; dst = WrT; R = DD; C = DD; bx = bid % 24; by = bid / 24; }
    else { int id = bid - 576; src = WK; dst = WKT; R = AA; C = DD; bx = id % 24; by = id / 24; }
    int tx = threadIdx.x & 31, ty = threadIdx.x >> 5;
    int c0 = bx * 32, r0 = by * 32;
#pragma unroll
    for (int k = 0; k < 4; ++k)
      tile[ty + 8 * k][tx] = src[(size_t)(r0 + ty + 8 * k) * C + c0 + tx];
    __syncthreads();
#pragma unroll
    for (int k = 0; k < 4; ++k)
      dst[(size_t)(c0 + ty + 8 * k) * R + r0 + tx] = tile[tx][ty + 8 * k];
  } else {
    int id = bid - 768;
    int b = id % BB, hg = id / BB;       // 8 h-groups of 12
    int t = threadIdx.x;
    if (t >= 192) return;                // 192 float4 = 768 floats
    const float* hb = hist + (size_t)b * HH * DD + (size_t)hg * 12 * DD + t * 4;
    float4 acc = make_float4(0.f, 0.f, 0.f, 0.f);
#pragma unroll
    for (int i = 0; i < 12; ++i) {
      float4 x = *(const float4*)(hb + (size_t)i * DD);
      acc.x += x.x; acc.y += x.y; acc.z += x.z; acc.w += x.w;
    }
    *(float4*)(neighp + ((size_t)hg * BB + b) * DD + t * 4) = acc;
  }
}

// ---------------------------------------------------------------------------
// D2 k_nl_u0: nl[b,e] = neigh[b,:]·W_l[e,:] + b_l[e];
//             u0[b,e] = hist[b,0,:]·W_r[e,:] + nl[b,e]
// wave-split-K, 3 b/thread, 32 e/block, grid (24, 32)
// ---------------------------------------------------------------------------
__global__ void k_nl_u0(const float* __restrict__ neighp, const float* __restrict__ hist,
                        const float* __restrict__ Wl, const float* __restrict__ bl,
                        const float* __restrict__ Wr,
                        float* __restrict__ nl, float* __restrict__ u0) {
  int e0 = blockIdx.x * 32;
  int b0 = blockIdx.y * 3;
  int lane = threadIdx.x & 63, wave = threadIdx.x >> 6;
  float4 xn[3][3], xh[3][3];
#pragma unroll
  for (int bi = 0; bi < 3; ++bi) {
    int b = b0 + bi;
#pragma unroll
    for (int jj = 0; jj < 3; ++jj) {
      int idx = lane + 64 * jj;
      float4 s = make_float4(0.f, 0.f, 0.f, 0.f);
#pragma unroll
      for (int g = 0; g < 8; ++g) {
        float4 x = ((const float4*)(neighp + ((size_t)g * BB + b) * DD))[idx];
        s.x += x.x; s.y += x.y; s.z += x.z; s.w += x.w;
      }
      xn[bi][jj] = make_float4(s.x * (1.f / 96.f), s.y * (1.f / 96.f),
                               s.z * (1.f / 96.f), s.w * (1.f / 96.f));
      xh[bi][jj] = ((const float4*)(hist + (size_t)b * HH * DD))[idx];  // h=0 row
    }
  }
  for (int i = 0; i < 8; ++i) {
    int e = e0 + wave * 8 + i;
    const float4* wl4 = (const float4*)(Wl + (size_t)e * DD);
    const float4* wr4 = (const float4*)(Wr + (size_t)e * DD);
    float pl[3] = {0.f, 0.f, 0.f}, pr[3] = {0.f, 0.f, 0.f};
#pragma unroll
    for (int jj = 0; jj < 3; ++jj) {
      float4 wl = wl4[lane + 64 * jj];
      float4 wr = wr4[lane + 64 * jj];
#pragma unroll
      for (int bi = 0; bi < 3; ++bi) {
        pl[bi] += dot4(wl, xn[bi][jj]);
        pr[bi] += dot4(wr, xh[bi][jj]);
      }
    }
#pragma unroll
    for (int bi = 0; bi < 3; ++bi) {
      float pp = pl[bi], qq = pr[bi];
      for (int off = 32; off; off >>= 1) {
        pp += __shfl_down(pp, off, 64);
        qq += __shfl_down(qq, off, 64);
      }
      if (lane == 0) {
        float nle = pp + bl[e];
        nl[(size_t)(b0 + bi) * DD + e] = nle;
        u0[(size_t)(b0 + bi) * DD + e] = qq + nle;
      }
    }
  }
}

// ---------------------------------------------------------------------------
// D3 k_head: per-b fused chain  Q = u0·WQ^T + bQ  ->  qk = Q·WK  ->  v = qk·Wr /16
// 96 blocks x 1024 threads (16 waves); intermediates in LDS.
// ---------------------------------------------------------------------------
__global__ void __launch_bounds__(1024)
k_head(const float* __restrict__ u0, const float* __restrict__ WQ,
       const float* __restrict__ bQ, const float* __restrict__ WKT,
       const float* __restrict__ WrT, float* __restrict__ vv) {
  int b = blockIdx.x;
  int tid = threadIdx.x, lane = tid & 63, wave = tid >> 6;
  __shared__ __align__(16) float s_u0[DD];
  __shared__ __align__(16) float s_Q[AA];
  __shared__ __align__(16) float s_qk[DD];
  if (tid < 192)
    ((float4*)s_u0)[tid] = ((const float4*)(u0 + (size_t)b * DD))[tid];
  __syncthreads();
  // Phase Q: 16 waves x 16 a's
  {
    float4 x0 = ((const float4*)s_u0)[lane];
    float4 x1 = ((const float4*)s_u0)[lane + 64];
    float4 x2 = ((const float4*)s_u0)[lane + 128];
    for (int i = 0; i < 16; ++i) {
      int a = wave * 16 + i;
      const float4* w4 = (const float4*)(WQ + (size_t)a * DD);
      float p = dot4(w4[lane], x0) + dot4(w4[lane + 64], x1) + dot4(w4[lane + 128], x2);
      for (int off = 32; off; off >>= 1) p += __shfl_down(p, off, 64);
      if (lane == 0) s_Q[a] = p + bQ[a];
    }
  }
  __syncthreads();
  // Phase qk: 16 waves x 48 d's; reduction over 256 = 64 lanes x 1 float4
  {
    float4 x = ((const float4*)s_Q)[lane];
    for (int i = 0; i < 48; ++i) {
      int d = wave * 48 + i;
      float4 w = ((const float4*)(WKT + (size_t)d * AA))[lane];
      float p = dot4(w, x);
      for (int off = 32; off; off >>= 1) p += __shfl_down(p, off, 64);
      if (lane == 0) s_qk[d] = p;
    }
  }
  __syncthreads();
  // Phase v: 16 waves x 48 c's; v[b,c] = (1/16) * sum_d qk[d] * WrT[c,d]
  {
    float4 x0 = ((const float4*)s_qk)[lane];
    float4 x1 = ((const float4*)s_qk)[lane + 64];
    float4 x2 = ((const float4*)s_qk)[lane + 128];
    for (int i = 0; i < 48; ++i) {
      int c = wave * 48 + i;
      const float4* w4 = (const float4*)(WrT + (size_t)c * DD);
      float p = dot4(w4[lane], x0) + dot4(w4[lane + 64], x1) + dot4(w4[lane + 128], x2);
      for (int off = 32; off; off >>= 1) p += __shfl_down(p, off, 64);
      if (lane == 0) vv[(size_t)b * DD + c] = p * (1.f / 16.f);
    }
  }
}

// ---------------------------------------------------------------------------
// D4 k_attn: per-b fused  scores -> softmax -> wsum
// 96 blocks x 1024 threads. scores: wave-split dots; softmax: wave 0 parallel;
// wsum: threads 0..767, column-coalesced, 4-wide h batching.
// ---------------------------------------------------------------------------
__global__ void __launch_bounds__(1024)
k_attn(const float* __restrict__ hist, const float* __restrict__ vv,
       float* __restrict__ wsum) {
  int b = blockIdx.x;
  int tid = threadIdx.x, lane = tid & 63, wave = tid >> 6;
  __shared__ __align__(16) float s_v[DD];
  __shared__ float s_al[HH];
  if (tid < 192)
    ((float4*)s_v)[tid] = ((const float4*)(vv + (size_t)b * DD))[tid];
  __syncthreads();
  // scores
  {
    float4 v0 = ((const float4*)s_v)[lane];
    float4 v1 = ((const float4*)s_v)[lane + 64];
    float4 v2 = ((const float4*)s_v)[lane + 128];
    const float* hb = hist + (size_t)b * HH * DD;
    for (int h = wave; h < HH; h += 16) {
      const float4* r = (const float4*)(hb + (size_t)h * DD);
      float p = dot4(r[lane], v0) + dot4(r[lane + 64], v1) + dot4(r[lane + 128], v2);
      for (int off = 32; off; off >>= 1) p += __shfl_down(p, off, 64);
      if (lane == 0) s_al[h] = p;
    }
  }
  __syncthreads();
  // softmax over 100 (wave 0, lanes hold h=lane and h=lane+64)
  if (wave == 0) {
    float x0 = (lane < HH) ? s_al[lane] : -1e30f;
    float x1 = (lane + 64 < HH) ? s_al[lane + 64] : -1e30f;
    float m = fmaxf(x0, x1);
    for (int off = 32; off; off >>= 1) m = fmaxf(m, __shfl_xor(m, off, 64));
    float e0 = (lane < HH) ? __expf(x0 - m) : 0.f;
    float e1 = (lane + 64 < HH) ? __expf(x1 - m) : 0.f;
    float s = e0 + e1;
    for (int off = 32; off; off >>= 1) s += __shfl_xor(s, off, 64);
    float inv = 1.f / s;
    if (lane < HH) s_al[lane] = e0 * inv;
    if (lane + 64 < HH) s_al[lane + 64] = e1 * inv;
  }
  __syncthreads();
  // wsum
  if (tid < DD) {
    const float* hb = hist + (size_t)b * HH * DD + tid;
    float acc = 0.f;
    for (int h = 0; h < HH; h += 4) {  // 100 % 4 == 0
      float v0 = hb[(size_t)(h + 0) * DD];
      float v1 = hb[(size_t)(h + 1) * DD];
      float v2 = hb[(size_t)(h + 2) * DD];
      float v3 = hb[(size_t)(h + 3) * DD];
      acc += s_al[h + 0] * v0 + s_al[h + 1] * v1 + s_al[h + 2] * v2 + s_al[h + 3] * v3;
    }
    wsum[(size_t)b * DD + tid] = acc;
  }
}

// ---------------------------------------------------------------------------
// D5 k_orow: orow[b,d] = nl[b,d] + wsum[b,:]·W_r[d,:]   grid (24, 32)
// ---------------------------------------------------------------------------
__global__ void k_orow(const float* __restrict__ wsum, const float* __restrict__ Wr,
                       const float* __restrict__ nl, float* __restrict__ orow) {
  int d0 = blockIdx.x * 32;
  int b0 = blockIdx.y * 3;
  int lane = threadIdx.x & 63, wave = threadIdx.x >> 6;
  float4 x[3][3];
#pragma unroll
  for (int bi = 0; bi < 3; ++bi)
#pragma unroll
    for (int jj = 0; jj < 3; ++jj)
      x[bi][jj] = ((const float4*)(wsum + (size_t)(b0 + bi) * DD))[lane + 64 * jj];
  for (int i = 0; i < 8; ++i) {
    int d = d0 + wave * 8 + i;
    const float4* w4 = (const float4*)(Wr + (size_t)d * DD);
    float p[3] = {0.f, 0.f, 0.f};
#pragma unroll
    for (int jj = 0; jj < 3; ++jj) {
      float4 w = w4[lane + 64 * jj];
#pragma unroll
      for (int bi = 0; bi < 3; ++bi) p[bi] += dot4(w, x[bi][jj]);
    }
#pragma unroll
    for (int bi = 0; bi < 3; ++bi) {
      float pp = p[bi];
      for (int off = 32; off; off >>= 1) pp += __shfl_down(pp, off, 64);
      if (lane == 0)
        orow[(size_t)(b0 + bi) * DD + d] = pp + nl[(size_t)(b0 + bi) * DD + d];
    }
  }
}

// ---------------------------------------------------------------------------
// D6 k_write: out[b,n,d] = orow[b,d]  — float4 per thread, fully coalesced
// ---------------------------------------------------------------------------
__global__ void k_write(const float* __restrict__ orow, float* __restrict__ out) {
  size_t t = (size_t)blockIdx.x * 256 + threadIdx.x;  // 2,359,296 threads
  int d4 = (int)(t % (DD / 4));
  int bn = (int)(t / (DD / 4));
  int b = bn >> 7;
  float4 v = *(const float4*)(orow + (size_t)b * DD + d4 * 4);
  *(float4*)(out + (size_t)bn * DD + d4 * 4) = v;
}

// ---------------------------------------------------------------------------
extern "C" void kernel_launch(void* const* d_in, const int* in_sizes, int n_in,
                              void* d_out, int out_size, void* d_ws, size_t ws_size,
                              hipStream_t stream) {
  const float *hist = nullptr, *Wl = nullptr, *Wr = nullptr, *WK = nullptr,
              *WQ = nullptr, *bl = nullptr, *bQ = nullptr;
  int seenDxD = 0, seenAxD = 0;
  for (int i = 0; i < n_in; ++i) {
    int s = in_sizes[i];
    const float* p = (const float*)d_in[i];
    if (s == BB * HH * DD) hist = p;
    else if (s == BB * NN * DD) { /* candidate — unused */ }
    else if (s == DD * DD) { if (seenDxD++ == 0) Wl = p; else Wr = p; }
    else if (s == AA * DD) { if (seenAxD++ == 0) WK = p; else WQ = p; }
    else if (s == DD) bl = p;
    else if (s == AA) bQ = p;
  }

  float* ws = (float*)d_ws;
  float* neighp = ws + 0;         // 8*96*768 = 589824
  float* WrT    = ws + 589824;    // 589824
  float* WKT    = ws + 1179648;   // 196608
  float* nl     = ws + 1376256;   // 73728
  float* u0     = ws + 1449984;   // 73728
  float* vv     = ws + 1523712;   // 73728
  float* wsum   = ws + 1597440;   // 73728
  float* orow   = ws + 1671168;   // 73728  -> total ~7 MB
  float* out = (float*)d_out;

  k_prep  <<<dim3(1536),   dim3(256),  0, stream>>>(Wr, WK, hist, WrT, WKT, neighp);
  k_nl_u0 <<<dim3(24, 32), dim3(256),  0, stream>>>(neighp, hist, Wl, bl, Wr, nl, u0);
  k_head  <<<dim3(BB),     dim3(1024), 0, stream>>>(u0, WQ, bQ, WKT, WrT, vv);
  k_attn  <<<dim3(BB),     dim3(1024), 0, stream>>>(hist, vv, wsum);
  k_orow  <<<dim3(24, 32), dim3(256),  0, stream>>>(wsum, Wr, nl, orow);
  k_write <<<dim3(9216),   dim3(256),  0, stream>>>(orow, out);
}

// Round 7
// 95.312 us; speedup vs baseline: 1.3262x; 1.3262x over previous
//
#include <hip/hip_runtime.h>
#include <hip/hip_bf16.h>

// Problem constants
#define BB 96    // batch
#define HH 100   // history length
#define NN 128   // candidates (broadcast only)
#define DD 768   // embed dim
#define AA 256   // attention dim

static __device__ __forceinline__ float dot4(float4 a, float4 b) {
  return a.x * b.x + a.y * b.y + a.z * b.z + a.w * b.w;
}

// ---------------------------------------------------------------------------
// D1 k_prep: grid-decoded fusion of all input-independent work:
//   blocks [0,576)    : transpose Wr (768x768) -> WrT
//   blocks [576,768)  : transpose WK (256x768) -> WKT
//   blocks [768,864)  : neigh[b,d] = mean_{h<96} hist[b,h,d]  (1 block/b)
// ---------------------------------------------------------------------------
__global__ void k_prep(const float* __restrict__ Wr, const float* __restrict__ WK,
                       const float* __restrict__ hist,
                       float* __restrict__ WrT, float* __restrict__ WKT,
                       float* __restrict__ neigh) {
  __shared__ float tile[32][33];
  int bid = blockIdx.x;
  if (bid < 768) {
    const float* src; float* dst; int R, C, bx, by;
    if (bid < 576) { src = Wr; dst = WrT; R = DD; C = DD; bx = bid % 24; by = bid / 24; }
    else { int id = bid - 576; src = WK; dst = WKT; R = AA; C = DD; bx = id % 24; by = id / 24; }
    int tx = threadIdx.x & 31, ty = threadIdx.x >> 5;
    int c0 = bx * 32, r0 = by * 32;
#pragma unroll
    for (int k = 0; k < 4; ++k)
      tile[ty + 8 * k][tx] = src[(size_t)(r0 + ty + 8 * k) * C + c0 + tx];
    __syncthreads();
#pragma unroll
    for (int k = 0; k < 4; ++k)
      dst[(size_t)(c0 + ty + 8 * k) * R + r0 + tx] = tile[tx][ty + 8 * k];
  } else {
    int b = bid - 768;
    int t = threadIdx.x;
    if (t >= 192) return;  // 192 float4 = 768 floats
    const float* hb = hist + (size_t)b * HH * DD + t * 4;
    float4 a0 = make_float4(0.f, 0.f, 0.f, 0.f);
    float4 a1 = make_float4(0.f, 0.f, 0.f, 0.f);
#pragma unroll 8
    for (int h = 0; h < 96; h += 2) {
      float4 x = *(const float4*)(hb + (size_t)h * DD);
      float4 y = *(const float4*)(hb + (size_t)(h + 1) * DD);
      a0.x += x.x; a0.y += x.y; a0.z += x.z; a0.w += x.w;
      a1.x += y.x; a1.y += y.y; a1.z += y.z; a1.w += y.w;
    }
    float4 m = make_float4((a0.x + a1.x) * (1.f / 96.f), (a0.y + a1.y) * (1.f / 96.f),
                           (a0.z + a1.z) * (1.f / 96.f), (a0.w + a1.w) * (1.f / 96.f));
    *(float4*)(neigh + (size_t)b * DD + t * 4) = m;
  }
}

// ---------------------------------------------------------------------------
// D2 k_nl_u0: nl[b,e] = neigh[b,:]·W_l[e,:] + b_l[e];
//             u0[b,e] = hist[b,0,:]·W_r[e,:] + nl[b,e]
// wave-split-K, 3 b/thread, 32 e/block, grid (24, 32)
// ---------------------------------------------------------------------------
__global__ void k_nl_u0(const float* __restrict__ neigh, const float* __restrict__ hist,
                        const float* __restrict__ Wl, const float* __restrict__ bl,
                        const float* __restrict__ Wr,
                        float* __restrict__ nl, float* __restrict__ u0) {
  int e0 = blockIdx.x * 32;
  int b0 = blockIdx.y * 3;
  int lane = threadIdx.x & 63, wave = threadIdx.x >> 6;
  float4 xn[3][3], xh[3][3];
#pragma unroll
  for (int bi = 0; bi < 3; ++bi) {
    int b = b0 + bi;
#pragma unroll
    for (int jj = 0; jj < 3; ++jj) {
      int idx = lane + 64 * jj;
      xn[bi][jj] = ((const float4*)(neigh + (size_t)b * DD))[idx];
      xh[bi][jj] = ((const float4*)(hist + (size_t)b * HH * DD))[idx];  // h=0 row
    }
  }
  for (int i = 0; i < 8; ++i) {
    int e = e0 + wave * 8 + i;
    const float4* wl4 = (const float4*)(Wl + (size_t)e * DD);
    const float4* wr4 = (const float4*)(Wr + (size_t)e * DD);
    float pl[3] = {0.f, 0.f, 0.f}, pr[3] = {0.f, 0.f, 0.f};
#pragma unroll
    for (int jj = 0; jj < 3; ++jj) {
      float4 wl = wl4[lane + 64 * jj];
      float4 wr = wr4[lane + 64 * jj];
#pragma unroll
      for (int bi = 0; bi < 3; ++bi) {
        pl[bi] += dot4(wl, xn[bi][jj]);
        pr[bi] += dot4(wr, xh[bi][jj]);
      }
    }
#pragma unroll
    for (int bi = 0; bi < 3; ++bi) {
      float pp = pl[bi], qq = pr[bi];
      for (int off = 32; off; off >>= 1) {
        pp += __shfl_down(pp, off, 64);
        qq += __shfl_down(qq, off, 64);
      }
      if (lane == 0) {
        float nle = pp + bl[e];
        nl[(size_t)(b0 + bi) * DD + e] = nle;
        u0[(size_t)(b0 + bi) * DD + e] = qq + nle;
      }
    }
  }
}

// ---------------------------------------------------------------------------
// D3 k_q: Q[b,a] = u0[b,:]·W_Q[a,:] + b_Q[a]   grid (8, 32)
// ---------------------------------------------------------------------------
__global__ void k_q(const float* __restrict__ u0, const float* __restrict__ WQ,
                    const float* __restrict__ bQ, float* __restrict__ Qm) {
  int a0 = blockIdx.x * 32;
  int b0 = blockIdx.y * 3;
  int lane = threadIdx.x & 63, wave = threadIdx.x >> 6;
  float4 x[3][3];
#pragma unroll
  for (int bi = 0; bi < 3; ++bi)
#pragma unroll
    for (int jj = 0; jj < 3; ++jj)
      x[bi][jj] = ((const float4*)(u0 + (size_t)(b0 + bi) * DD))[lane + 64 * jj];
  for (int i = 0; i < 8; ++i) {
    int a = a0 + wave * 8 + i;
    const float4* w4 = (const float4*)(WQ + (size_t)a * DD);
    float p[3] = {0.f, 0.f, 0.f};
#pragma unroll
    for (int jj = 0; jj < 3; ++jj) {
      float4 w = w4[lane + 64 * jj];
#pragma unroll
      for (int bi = 0; bi < 3; ++bi) p[bi] += dot4(w, x[bi][jj]);
    }
#pragma unroll
    for (int bi = 0; bi < 3; ++bi) {
      float pp = p[bi];
      for (int off = 32; off; off >>= 1) pp += __shfl_down(pp, off, 64);
      if (lane == 0) Qm[(size_t)(b0 + bi) * AA + a] = pp + bQ[a];
    }
  }
}

// ---------------------------------------------------------------------------
// D4 k_qk: qk[b,d] = Q[b,:]·WKT[d,:]   grid (24, 32)
// ---------------------------------------------------------------------------
__global__ void k_qk(const float* __restrict__ Qm, const float* __restrict__ WKT,
                     float* __restrict__ qk) {
  int d0 = blockIdx.x * 32;
  int b0 = blockIdx.y * 3;
  int lane = threadIdx.x & 63, wave = threadIdx.x >> 6;
  float4 x[3];
#pragma unroll
  for (int bi = 0; bi < 3; ++bi)
    x[bi] = ((const float4*)(Qm + (size_t)(b0 + bi) * AA))[lane];
  for (int i = 0; i < 8; ++i) {
    int d = d0 + wave * 8 + i;
    float4 w = ((const float4*)(WKT + (size_t)d * AA))[lane];
    float p[3];
#pragma unroll
    for (int bi = 0; bi < 3; ++bi) p[bi] = dot4(w, x[bi]);
#pragma unroll
    for (int bi = 0; bi < 3; ++bi) {
      float pp = p[bi];
      for (int off = 32; off; off >>= 1) pp += __shfl_down(pp, off, 64);
      if (lane == 0) qk[(size_t)(b0 + bi) * DD + d] = pp;
    }
  }
}

// ---------------------------------------------------------------------------
// D5 k_v: v[b,d] = (1/16) * qk[b,:]·WrT[d,:]   grid (24, 32)
// ---------------------------------------------------------------------------
__global__ void k_v(const float* __restrict__ qk, const float* __restrict__ WrT,
                    float* __restrict__ vv) {
  int d0 = blockIdx.x * 32;
  int b0 = blockIdx.y * 3;
  int lane = threadIdx.x & 63, wave = threadIdx.x >> 6;
  float4 x[3][3];
#pragma unroll
  for (int bi = 0; bi < 3; ++bi)
#pragma unroll
    for (int jj = 0; jj < 3; ++jj)
      x[bi][jj] = ((const float4*)(qk + (size_t)(b0 + bi) * DD))[lane + 64 * jj];
  for (int i = 0; i < 8; ++i) {
    int d = d0 + wave * 8 + i;
    const float4* w4 = (const float4*)(WrT + (size_t)d * DD);
    float p[3] = {0.f, 0.f, 0.f};
#pragma unroll
    for (int jj = 0; jj < 3; ++jj) {
      float4 w = w4[lane + 64 * jj];
#pragma unroll
      for (int bi = 0; bi < 3; ++bi) p[bi] += dot4(w, x[bi][jj]);
    }
#pragma unroll
    for (int bi = 0; bi < 3; ++bi) {
      float pp = p[bi];
      for (int off = 32; off; off >>= 1) pp += __shfl_down(pp, off, 64);
      if (lane == 0) vv[(size_t)(b0 + bi) * DD + d] = pp * (1.f / 16.f);
    }
  }
}

// ---------------------------------------------------------------------------
// D6 k_scores: scores[b,h] = hist[b,h,:]·v[b,:]   grid (96, 5), 20 h/block
// ---------------------------------------------------------------------------
__global__ void k_scores(const float* __restrict__ hist, const float* __restrict__ vv,
                         float* __restrict__ sc) {
  int b = blockIdx.x, hg = blockIdx.y;
  int lane = threadIdx.x & 63, wave = threadIdx.x >> 6;
  float4 v[3];
  const float4* vb = (const float4*)(vv + (size_t)b * DD);
#pragma unroll
  for (int jj = 0; jj < 3; ++jj) v[jj] = vb[lane + 64 * jj];
  const float* hb = hist + (size_t)b * HH * DD;
  for (int i = 0; i < 5; ++i) {
    int h = hg * 20 + wave * 5 + i;
    const float4* r = (const float4*)(hb + (size_t)h * DD);
    float p = 0.f;
#pragma unroll
    for (int jj = 0; jj < 3; ++jj) p += dot4(r[lane + 64 * jj], v[jj]);
    for (int off = 32; off; off >>= 1) p += __shfl_down(p, off, 64);
    if (lane == 0) sc[b * 128 + h] = p;
  }
}

// ---------------------------------------------------------------------------
// D7 k_wsum: softmax over h (once per block in LDS) + weighted hist sum
// grid (96, 3)
// ---------------------------------------------------------------------------
__global__ void k_wsum(const float* __restrict__ hist, const float* __restrict__ sc,
                       float* __restrict__ wsum) {
  int b = blockIdx.x;
  int e = blockIdx.y * 256 + threadIdx.x;
  __shared__ float sal[HH];
  __shared__ float s_inv;
  if (threadIdx.x < HH) sal[threadIdx.x] = sc[b * 128 + threadIdx.x];
  __syncthreads();
  if (threadIdx.x == 0) {
    float m = -1e30f;
    for (int h = 0; h < HH; ++h) m = fmaxf(m, sal[h]);
    float s = 0.f;
    for (int h = 0; h < HH; ++h) { float ex = __expf(sal[h] - m); sal[h] = ex; s += ex; }
    s_inv = 1.f / s;
  }
  __syncthreads();
  float inv = s_inv;
  float acc = 0.f;
  const float* hb = hist + (size_t)b * HH * DD + e;
  for (int h = 0; h < HH; h += 4) {  // 100 % 4 == 0
    float v0 = hb[(size_t)(h + 0) * DD];
    float v1 = hb[(size_t)(h + 1) * DD];
    float v2 = hb[(size_t)(h + 2) * DD];
    float v3 = hb[(size_t)(h + 3) * DD];
    acc += sal[h + 0] * v0 + sal[h + 1] * v1 + sal[h + 2] * v2 + sal[h + 3] * v3;
  }
  wsum[(size_t)b * DD + e] = acc * inv;
}

// ---------------------------------------------------------------------------
// D8 k_orow_write: orow[b,d] = nl[b,d] + wsum[b,:]·W_r[d,:], then broadcast
// directly to out[b, 0..127, d] (via LDS stage). grid (24, 32).
// ---------------------------------------------------------------------------
__global__ void k_orow_write(const float* __restrict__ wsum, const float* __restrict__ Wr,
                             const float* __restrict__ nl, float* __restrict__ out) {
  int d0 = blockIdx.x * 32;
  int b0 = blockIdx.y * 3;
  int lane = threadIdx.x & 63, wave = threadIdx.x >> 6;
  __shared__ __align__(16) float s_o[3][32];
  float4 x[3][3];
#pragma unroll
  for (int bi = 0; bi < 3; ++bi)
#pragma unroll
    for (int jj = 0; jj < 3; ++jj)
      x[bi][jj] = ((const float4*)(wsum + (size_t)(b0 + bi) * DD))[lane + 64 * jj];
  for (int i = 0; i < 8; ++i) {
    int d = d0 + wave * 8 + i;
    const float4* w4 = (const float4*)(Wr + (size_t)d * DD);
    float p[3] = {0.f, 0.f, 0.f};
#pragma unroll
    for (int jj = 0; jj < 3; ++jj) {
      float4 w = w4[lane + 64 * jj];
#pragma unroll
      for (int bi = 0; bi < 3; ++bi) p[bi] += dot4(w, x[bi][jj]);
    }
#pragma unroll
    for (int bi = 0; bi < 3; ++bi) {
      float pp = p[bi];
      for (int off = 32; off; off >>= 1) pp += __shfl_down(pp, off, 64);
      if (lane == 0)
        s_o[bi][wave * 8 + i] = pp + nl[(size_t)(b0 + bi) * DD + d];
    }
  }
  __syncthreads();
  // Broadcast: 3 b x 128 n x 8 float4 = 3072 float4 writes, 12 per thread.
  // Segment = (bi, n): 8 consecutive threads write its 32 floats (128 B).
  float4* out4 = (float4*)out;
  int d4 = d0 >> 2;  // float4 offset of d0 within a 192-float4 row
#pragma unroll
  for (int k = 0; k < 12; ++k) {
    int g = threadIdx.x + (k << 8);
    int seg = g >> 3, off = g & 7;
    int bi = seg >> 7, n = seg & 127;
    float4 val = *(const float4*)&s_o[bi][off * 4];
    out4[((size_t)(b0 + bi) * NN + n) * (DD / 4) + d4 + off] = val;
  }
}

// ---------------------------------------------------------------------------
extern "C" void kernel_launch(void* const* d_in, const int* in_sizes, int n_in,
                              void* d_out, int out_size, void* d_ws, size_t ws_size,
                              hipStream_t stream) {
  const float *hist = nullptr, *Wl = nullptr, *Wr = nullptr, *WK = nullptr,
              *WQ = nullptr, *bl = nullptr, *bQ = nullptr;
  int seenDxD = 0, seenAxD = 0;
  for (int i = 0; i < n_in; ++i) {
    int s = in_sizes[i];
    const float* p = (const float*)d_in[i];
    if (s == BB * HH * DD) hist = p;
    else if (s == BB * NN * DD) { /* candidate — unused */ }
    else if (s == DD * DD) { if (seenDxD++ == 0) Wl = p; else Wr = p; }
    else if (s == AA * DD) { if (seenAxD++ == 0) WK = p; else WQ = p; }
    else if (s == DD) bl = p;
    else if (s == AA) bQ = p;
  }

  float* ws = (float*)d_ws;
  float* WrT   = ws + 0;         // 589824
  float* WKT   = ws + 589824;    // 196608
  float* neigh = ws + 786432;    // 73728
  float* nl    = ws + 860160;    // 73728
  float* u0    = ws + 933888;    // 73728
  float* Qm    = ws + 1007616;   // 24576
  float* qk    = ws + 1032192;   // 73728
  float* vv    = ws + 1105920;   // 73728
  float* sc    = ws + 1179648;   // 12288
  float* wsum  = ws + 1191936;   // 73728  -> total ~5.1 MB
  float* out = (float*)d_out;

  k_prep      <<<dim3(864),    dim3(256), 0, stream>>>(Wr, WK, hist, WrT, WKT, neigh);
  k_nl_u0     <<<dim3(24, 32), dim3(256), 0, stream>>>(neigh, hist, Wl, bl, Wr, nl, u0);
  k_q         <<<dim3(8, 32),  dim3(256), 0, stream>>>(u0, WQ, bQ, Qm);
  k_qk        <<<dim3(24, 32), dim3(256), 0, stream>>>(Qm, WKT, qk);
  k_v         <<<dim3(24, 32), dim3(256), 0, stream>>>(qk, WrT, vv);
  k_scores    <<<dim3(96, 5),  dim3(256), 0, stream>>>(hist, vv, sc);
  k_wsum      <<<dim3(96, 3),  dim3(256), 0, stream>>>(hist, sc, wsum);
  k_orow_write<<<dim3(24, 32), dim3(256), 0, stream>>>(wsum, Wr, nl, out);
}